// Round 4
// baseline (768.304 us; speedup 1.0000x reference)
//
#include <hip/hip_runtime.h>
#include <hip/hip_bf16.h>
#include <hip/hip_cooperative_groups.h>

namespace cg = cooperative_groups;

#define NFEAT 256
#define NQ    64          // NFEAT/4 float4 quads
#define CH    256         // rows per chunk
#define GRID  1024        // 4 blocks/CU x 256 CU — cooperative-safe
#define BLK   256
#define STRIPS 8

typedef float f32x4_native __attribute__((ext_vector_type(4)));

__device__ __forceinline__ void nt_store4(float4* p, float4 v) {
    f32x4_native n; n.x = v.x; n.y = v.y; n.z = v.z; n.w = v.w;
    __builtin_nontemporal_store(n, reinterpret_cast<f32x4_native*>(p));
}

__global__ __launch_bounds__(BLK, 4) void k_fused(
    const float* __restrict__ x, const int* __restrict__ lengths,
    const float* __restrict__ weight, const float* __restrict__ bias,
    float* __restrict__ out, int B,
    int* __restrict__ off_g, int* __restrict__ bs_g,
    float* __restrict__ psum, float* __restrict__ psumsq,
    float* __restrict__ psum2, float* __restrict__ psumsq2,
    float* __restrict__ scale_g, float* __restrict__ shift_g)
{
    cg::grid_group grid = cg::this_grid();
    const int t   = threadIdx.x;
    const int bid = blockIdx.x;

    __shared__ int soff[132], sbs[132];
    __shared__ float4 red[2][4][NQ];

    // ---------------- Phase 0: block 0 scans lengths -> off/bs --------------
    if (bid == 0) {
        __shared__ int L[BLK], C[BLK];
        int len = (t < B) ? lengths[t] : 0;
        L[t] = len;
        C[t] = (len + CH - 1) / CH;
        __syncthreads();
        for (int d = 1; d < BLK; d <<= 1) {         // Hillis-Steele inclusive
            int a = L[t], c = C[t], aa = 0, cc = 0;
            if (t >= d) { aa = L[t - d]; cc = C[t - d]; }
            __syncthreads();
            L[t] = a + aa; C[t] = c + cc;
            __syncthreads();
        }
        if (t == 0) { off_g[0] = 0; bs_g[0] = 0; }
        if (t < B)  { off_g[t + 1] = L[t]; bs_g[t + 1] = C[t]; }
    }
    grid.sync();

    // all blocks: cache off/bs in LDS
    if (t <= B) { soff[t] = off_g[t]; sbs[t] = bs_g[t]; }
    __syncthreads();
    const int nch = sbs[B];

    const int rl = t >> 6;          // row lane 0..3
    const int q  = t & 63;          // feature quad
    const float4* x4 = reinterpret_cast<const float4*>(x);

    // ---------------- Phase 1: balanced per-chunk partials ------------------
    for (int c = bid; c < nch; c += GRID) {
        int lo = 0, hi = B;
        while (hi - lo > 1) { int mid = (lo + hi) >> 1; if (sbs[mid] <= c) lo = mid; else hi = mid; }
        const int seg = lo;
        const int r0 = soff[seg] + (c - sbs[seg]) * CH;
        const int r1 = min(r0 + CH, soff[seg + 1]);

        float4 sum = make_float4(0.f, 0.f, 0.f, 0.f);
        float4 sq  = make_float4(0.f, 0.f, 0.f, 0.f);
        #pragma unroll 4
        for (int r = r0 + rl; r < r1; r += 4) {
            float4 v = x4[(size_t)r * NQ + q];
            sum.x += v.x; sum.y += v.y; sum.z += v.z; sum.w += v.w;
            sq.x  += v.x * v.x; sq.y += v.y * v.y; sq.z += v.z * v.z; sq.w += v.w * v.w;
        }
        red[0][rl][q] = sum;
        red[1][rl][q] = sq;
        __syncthreads();
        if (rl == 0) {
            float4 a0 = red[0][0][q], a1 = red[0][1][q], a2 = red[0][2][q], a3 = red[0][3][q];
            float4 q0 = red[1][0][q], q1 = red[1][1][q], q2 = red[1][2][q], q3 = red[1][3][q];
            float4 ts, tq;
            ts.x = a0.x + a1.x + a2.x + a3.x;  ts.y = a0.y + a1.y + a2.y + a3.y;
            ts.z = a0.z + a1.z + a2.z + a3.z;  ts.w = a0.w + a1.w + a2.w + a3.w;
            tq.x = q0.x + q1.x + q2.x + q3.x;  tq.y = q0.y + q1.y + q2.y + q3.y;
            tq.z = q0.z + q1.z + q2.z + q3.z;  tq.w = q0.w + q1.w + q2.w + q3.w;
            reinterpret_cast<float4*>(psum)[(size_t)c * NQ + q]   = ts;
            reinterpret_cast<float4*>(psumsq)[(size_t)c * NQ + q] = tq;
        }
        __syncthreads();
    }
    grid.sync();

    // ---------------- Phase 2a: strip-reduce partials per segment -----------
    for (int it = bid; it < B * STRIPS; it += GRID) {
        const int seg = it % B, strip = it / B;
        const int c0 = sbs[seg], c1 = sbs[seg + 1];
        const int ncs  = c1 - c0;
        const int step = (ncs + STRIPS - 1) / STRIPS;
        const int a0 = c0 + strip * step;
        const int a1 = min(a0 + step, c1);
        float s = 0.f, ss = 0.f;
        for (int cc = a0; cc < a1; ++cc) {
            s  += psum[(size_t)cc * NFEAT + t];
            ss += psumsq[(size_t)cc * NFEAT + t];
        }
        psum2[((size_t)strip * B + seg) * NFEAT + t]   = s;
        psumsq2[((size_t)strip * B + seg) * NFEAT + t] = ss;
    }
    grid.sync();

    // ---------------- Phase 2b: finalize -> scale/shift ---------------------
    for (int seg = bid; seg < B; seg += GRID) {
        float s = 0.f, ss = 0.f;
        #pragma unroll
        for (int st = 0; st < STRIPS; ++st) {
            s  += psum2[((size_t)st * B + seg) * NFEAT + t];
            ss += psumsq2[((size_t)st * B + seg) * NFEAT + t];
        }
        const float cnt = (float)(soff[seg + 1] - soff[seg]);
        const float m   = s / cnt;
        const float var = fmaxf(ss / cnt - m * m, 0.f);
        const float rstd = rsqrtf(var + 1e-5f);
        const float sc = rstd * weight[t];
        const float sh = bias[t] - m * sc;
        scale_g[(size_t)seg * NFEAT + t] = sc;
        shift_g[(size_t)seg * NFEAT + t] = sh;
    }
    grid.sync();

    // ---------------- Phase 3: normalize ------------------------------------
    const float4* sc4 = reinterpret_cast<const float4*>(scale_g);
    const float4* sh4 = reinterpret_cast<const float4*>(shift_g);
    float4* o4 = reinterpret_cast<float4*>(out);
    for (int c = bid; c < nch; c += GRID) {
        int lo = 0, hi = B;
        while (hi - lo > 1) { int mid = (lo + hi) >> 1; if (sbs[mid] <= c) lo = mid; else hi = mid; }
        const int seg = lo;
        const int r0 = soff[seg] + (c - sbs[seg]) * CH;
        const int r1 = min(r0 + CH, soff[seg + 1]);

        const float4 sc = sc4[(size_t)seg * NQ + q];
        const float4 sh = sh4[(size_t)seg * NQ + q];

        #pragma unroll 4
        for (int r = r0 + rl; r < r1; r += 4) {
            const size_t idx = (size_t)r * NQ + q;
            float4 v = x4[idx];
            float4 o;
            o.x = v.x * sc.x + sh.x;
            o.y = v.y * sc.y + sh.y;
            o.z = v.z * sc.z + sh.z;
            o.w = v.w * sc.w + sh.w;
            nt_store4(&o4[idx], o);
        }
    }
}

extern "C" void kernel_launch(void* const* d_in, const int* in_sizes, int n_in,
                              void* d_out, int out_size, void* d_ws, size_t ws_size,
                              hipStream_t stream) {
    const float* x       = (const float*)d_in[0];
    const int*   lengths = (const int*)d_in[1];
    const float* weight  = (const float*)d_in[2];
    const float* bias    = (const float*)d_in[3];
    float*       out     = (float*)d_out;

    int B = in_sizes[1];                     // 128 segments
    const int N = in_sizes[0] / NFEAT;       // 524288 rows
    const int maxCh = N / CH + B;            // chunk upper bound

    // ws layout (aligned chunks)
    char* ws = (char*)d_ws;
    int*   off_g   = (int*)ws;                                   // B+1
    int*   bs_g    = off_g + 160;                                // B+1
    float* scale_g = (float*)(ws + 4096);                        // B*F
    float* shift_g = scale_g + (size_t)B * NFEAT;                // B*F
    float* psum2   = shift_g + (size_t)B * NFEAT;                // STRIPS*B*F
    float* psumsq2 = psum2 + (size_t)STRIPS * B * NFEAT;         // STRIPS*B*F
    float* psum    = psumsq2 + (size_t)STRIPS * B * NFEAT;       // maxCh*F
    float* psumsq  = psum + (size_t)maxCh * NFEAT;               // maxCh*F

    void* args[] = { (void*)&x, (void*)&lengths, (void*)&weight, (void*)&bias,
                     (void*)&out, (void*)&B,
                     (void*)&off_g, (void*)&bs_g,
                     (void*)&psum, (void*)&psumsq,
                     (void*)&psum2, (void*)&psumsq2,
                     (void*)&scale_g, (void*)&shift_g };
    hipLaunchCooperativeKernel((void*)k_fused, dim3(GRID), dim3(BLK), args, 0, stream);
}

// Round 5
// 352.517 us; speedup vs baseline: 2.1795x; 2.1795x over previous
//
#include <hip/hip_runtime.h>
#include <hip/hip_bf16.h>

#define NFEAT 256
#define NQ    64          // NFEAT/4 float4 quads
#define CH    256         // rows per balanced chunk
#define BLK   256

typedef float f32x4_native __attribute__((ext_vector_type(4)));

__device__ __forceinline__ void nt_store4(float4* p, float4 v) {
    f32x4_native n; n.x = v.x; n.y = v.y; n.z = v.z; n.w = v.w;
    __builtin_nontemporal_store(n, reinterpret_cast<f32x4_native*>(p));
}

// ---------------------------------------------------------------------------
// Kernel 0: parallel Hillis-Steele scan of lengths -> off[B+1], bs[B+1], nblk.
// (Round 1/2 had thread-0 serially pointer-chasing 128 global loads ~35us.)
// ---------------------------------------------------------------------------
__global__ __launch_bounds__(BLK) void k_setup(const int* __restrict__ lengths, int B,
                                               int* __restrict__ off, int* __restrict__ bs,
                                               int* __restrict__ nblk) {
    __shared__ int L[BLK], C[BLK];
    const int t = threadIdx.x;
    int len = (t < B) ? lengths[t] : 0;
    L[t] = len;
    C[t] = (len + CH - 1) / CH;
    __syncthreads();
    for (int d = 1; d < BLK; d <<= 1) {
        int a = L[t], c = C[t], aa = 0, cc = 0;
        if (t >= d) { aa = L[t - d]; cc = C[t - d]; }
        __syncthreads();
        L[t] = a + aa; C[t] = c + cc;
        __syncthreads();
    }
    if (t == 0) { off[0] = 0; bs[0] = 0; }
    if (t < B)  { off[t + 1] = L[t]; bs[t + 1] = C[t]; }
    if (t == B - 1) *nblk = C[t];
}

// Block bid -> segment s with bs[s] <= bid < bs[s+1] (parallel range test).
__device__ __forceinline__ int find_seg(const int* __restrict__ bs, int B, int bid) {
    __shared__ int sseg;
    const int t = threadIdx.x;
    if (t < B && bs[t] <= bid && bid < bs[t + 1]) sseg = t;
    __syncthreads();
    return sseg;
}

// ---------------------------------------------------------------------------
// Kernel 1: per-chunk partial sum / sum-of-squares per feature.
// Block = 4 row-lanes x 64 feature-quads; CH=256 rows -> 64 iters/thread.
// ---------------------------------------------------------------------------
__global__ __launch_bounds__(BLK) void k_partial(const float* __restrict__ x,
                                                 const int* __restrict__ off,
                                                 const int* __restrict__ bs,
                                                 const int* __restrict__ nblk,
                                                 int B,
                                                 float* __restrict__ psum,
                                                 float* __restrict__ psumsq) {
    const int bid = blockIdx.x;
    if (bid >= *nblk) return;

    const int seg = find_seg(bs, B, bid);
    const int r0 = off[seg] + (bid - bs[seg]) * CH;
    const int r1 = min(r0 + CH, off[seg + 1]);

    const int rl = threadIdx.x >> 6;   // 0..3
    const int q  = threadIdx.x & 63;

    float4 sum = make_float4(0.f, 0.f, 0.f, 0.f);
    float4 sq  = make_float4(0.f, 0.f, 0.f, 0.f);

    const float4* x4 = reinterpret_cast<const float4*>(x);
    #pragma unroll 8
    for (int r = r0 + rl; r < r1; r += 4) {
        float4 v = x4[(size_t)r * NQ + q];
        sum.x += v.x; sum.y += v.y; sum.z += v.z; sum.w += v.w;
        sq.x  += v.x * v.x; sq.y += v.y * v.y; sq.z += v.z * v.z; sq.w += v.w * v.w;
    }

    __shared__ float4 lsum[4][NQ];
    __shared__ float4 lsq[4][NQ];
    lsum[rl][q] = sum;
    lsq[rl][q]  = sq;
    __syncthreads();

    if (rl == 0) {
        float4 a0 = lsum[0][q], a1 = lsum[1][q], a2 = lsum[2][q], a3 = lsum[3][q];
        float4 q0 = lsq[0][q],  q1 = lsq[1][q],  q2 = lsq[2][q],  q3 = lsq[3][q];
        float4 ts, tq;
        ts.x = a0.x + a1.x + a2.x + a3.x;  ts.y = a0.y + a1.y + a2.y + a3.y;
        ts.z = a0.z + a1.z + a2.z + a3.z;  ts.w = a0.w + a1.w + a2.w + a3.w;
        tq.x = q0.x + q1.x + q2.x + q3.x;  tq.y = q0.y + q1.y + q2.y + q3.y;
        tq.z = q0.z + q1.z + q2.z + q3.z;  tq.w = q0.w + q1.w + q2.w + q3.w;
        reinterpret_cast<float4*>(psum)[(size_t)bid * NQ + q]   = ts;
        reinterpret_cast<float4*>(psumsq)[(size_t)bid * NQ + q] = tq;
    }
}

// ---------------------------------------------------------------------------
// Kernel 2: reduce each segment's contiguous chunk range -> scale/shift.
// ---------------------------------------------------------------------------
__global__ __launch_bounds__(BLK) void k_finalize(const float* __restrict__ psum,
                                                  const float* __restrict__ psumsq,
                                                  const int* __restrict__ off,
                                                  const int* __restrict__ bs,
                                                  const float* __restrict__ weight,
                                                  const float* __restrict__ bias,
                                                  float* __restrict__ scale,
                                                  float* __restrict__ shift) {
    const int seg = blockIdx.x;
    const int f   = threadIdx.x;
    const int b0 = bs[seg], b1 = bs[seg + 1];
    float s = 0.f, qq = 0.f;
    for (int b = b0; b < b1; ++b) {
        s  += psum[(size_t)b * NFEAT + f];
        qq += psumsq[(size_t)b * NFEAT + f];
    }
    const float cnt  = (float)(off[seg + 1] - off[seg]);
    const float m    = s / cnt;
    const float var  = fmaxf(qq / cnt - m * m, 0.f);
    const float rstd = rsqrtf(var + 1e-5f);
    const float sc   = rstd * weight[f];
    scale[(size_t)seg * NFEAT + f] = sc;
    shift[(size_t)seg * NFEAT + f] = bias[f] - m * sc;
}

// ---------------------------------------------------------------------------
// Kernel 3: normalize. Regular x loads (want L3 hits from the stats pass);
// NON-TEMPORAL out stores (zero reuse -> don't evict x from caches).
// ---------------------------------------------------------------------------
__global__ __launch_bounds__(BLK) void k_norm(const float* __restrict__ x,
                                              const int* __restrict__ off,
                                              const int* __restrict__ bs,
                                              const int* __restrict__ nblk,
                                              int B,
                                              const float* __restrict__ scale,
                                              const float* __restrict__ shift,
                                              float* __restrict__ out) {
    const int bid = blockIdx.x;
    if (bid >= *nblk) return;

    const int seg = find_seg(bs, B, bid);
    const int r0 = off[seg] + (bid - bs[seg]) * CH;
    const int r1 = min(r0 + CH, off[seg + 1]);

    const int rl = threadIdx.x >> 6;
    const int q  = threadIdx.x & 63;

    const float4 sc = reinterpret_cast<const float4*>(scale)[(size_t)seg * NQ + q];
    const float4 sh = reinterpret_cast<const float4*>(shift)[(size_t)seg * NQ + q];

    const float4* x4 = reinterpret_cast<const float4*>(x);
    float4* o4 = reinterpret_cast<float4*>(out);
    #pragma unroll 8
    for (int r = r0 + rl; r < r1; r += 4) {
        const size_t idx = (size_t)r * NQ + q;
        float4 v = x4[idx];
        float4 o;
        o.x = v.x * sc.x + sh.x;
        o.y = v.y * sc.y + sh.y;
        o.z = v.z * sc.z + sh.z;
        o.w = v.w * sc.w + sh.w;
        nt_store4(&o4[idx], o);
    }
}

extern "C" void kernel_launch(void* const* d_in, const int* in_sizes, int n_in,
                              void* d_out, int out_size, void* d_ws, size_t ws_size,
                              hipStream_t stream) {
    const float* x       = (const float*)d_in[0];
    const int*   lengths = (const int*)d_in[1];
    const float* weight  = (const float*)d_in[2];
    const float* bias    = (const float*)d_in[3];
    float*       out     = (float*)d_out;

    const int B = in_sizes[1];               // 128
    const int N = in_sizes[0] / NFEAT;       // 524288
    const int maxCh = N / CH + B;            // chunk upper bound (2176)

    // ws layout
    char* ws = (char*)d_ws;
    int*   off    = (int*)ws;                                  // B+1
    int*   bs     = off + 160;                                 // B+1
    int*   nblk   = bs + 160;                                  // 1
    float* scale  = (float*)(ws + 4096);                       // B*F
    float* shift  = scale + (size_t)B * NFEAT;                 // B*F
    float* psum   = shift + (size_t)B * NFEAT;                 // maxCh*F
    float* psumsq = psum + (size_t)maxCh * NFEAT;              // maxCh*F

    k_setup<<<1, BLK, 0, stream>>>(lengths, B, off, bs, nblk);
    k_partial<<<maxCh, BLK, 0, stream>>>(x, off, bs, nblk, B, psum, psumsq);
    k_finalize<<<B, BLK, 0, stream>>>(psum, psumsq, off, bs, weight, bias, scale, shift);
    k_norm<<<maxCh, BLK, 0, stream>>>(x, off, bs, nblk, B, scale, shift, out);
}

// Round 6
// 319.402 us; speedup vs baseline: 2.4054x; 1.1037x over previous
//
#include <hip/hip_runtime.h>
#include <hip/hip_bf16.h>

#define NFEAT 256
#define NQ    64          // NFEAT/4 float4 quads
#define CH    256         // rows per balanced chunk
#define BLK   256

typedef float f32x4_native __attribute__((ext_vector_type(4)));

__device__ __forceinline__ void nt_store4(float4* p, float4 v) {
    f32x4_native n; n.x = v.x; n.y = v.y; n.z = v.z; n.w = v.w;
    __builtin_nontemporal_store(n, reinterpret_cast<f32x4_native*>(p));
}

// ---------------------------------------------------------------------------
// Kernel 0: parallel Hillis-Steele scan of lengths -> off[B+1], bs[B+1], nblk.
// ---------------------------------------------------------------------------
__global__ __launch_bounds__(BLK) void k_setup(const int* __restrict__ lengths, int B,
                                               int* __restrict__ off, int* __restrict__ bs,
                                               int* __restrict__ nblk) {
    __shared__ int L[BLK], C[BLK];
    const int t = threadIdx.x;
    int len = (t < B) ? lengths[t] : 0;
    L[t] = len;
    C[t] = (len + CH - 1) / CH;
    __syncthreads();
    for (int d = 1; d < BLK; d <<= 1) {
        int a = L[t], c = C[t], aa = 0, cc = 0;
        if (t >= d) { aa = L[t - d]; cc = C[t - d]; }
        __syncthreads();
        L[t] = a + aa; C[t] = c + cc;
        __syncthreads();
    }
    if (t == 0) { off[0] = 0; bs[0] = 0; }
    if (t < B)  { off[t + 1] = L[t]; bs[t + 1] = C[t]; }
    if (t == B - 1) *nblk = C[t];
}

// Chunk c -> segment s with bs[s] <= c < bs[s+1] (parallel range test).
__device__ __forceinline__ int find_seg(const int* __restrict__ bs, int B, int c) {
    __shared__ int sseg;
    const int t = threadIdx.x;
    if (t < B && bs[t] <= c && c < bs[t + 1]) sseg = t;
    __syncthreads();
    return sseg;
}

// ---------------------------------------------------------------------------
// Kernel 1: per-chunk partial sum / sum-of-squares per feature.
// Regular loads: we WANT x resident in L3 for k_norm's reversed re-read.
// ---------------------------------------------------------------------------
__global__ __launch_bounds__(BLK) void k_partial(const float* __restrict__ x,
                                                 const int* __restrict__ off,
                                                 const int* __restrict__ bs,
                                                 const int* __restrict__ nblk,
                                                 int B,
                                                 float* __restrict__ psum,
                                                 float* __restrict__ psumsq) {
    const int bid = blockIdx.x;
    if (bid >= *nblk) return;

    const int seg = find_seg(bs, B, bid);
    const int r0 = off[seg] + (bid - bs[seg]) * CH;
    const int r1 = min(r0 + CH, off[seg + 1]);

    const int rl = threadIdx.x >> 6;   // 0..3
    const int q  = threadIdx.x & 63;

    float4 sum = make_float4(0.f, 0.f, 0.f, 0.f);
    float4 sq  = make_float4(0.f, 0.f, 0.f, 0.f);

    const float4* x4 = reinterpret_cast<const float4*>(x);
    #pragma unroll 8
    for (int r = r0 + rl; r < r1; r += 4) {
        float4 v = x4[(size_t)r * NQ + q];
        sum.x += v.x; sum.y += v.y; sum.z += v.z; sum.w += v.w;
        sq.x  += v.x * v.x; sq.y += v.y * v.y; sq.z += v.z * v.z; sq.w += v.w * v.w;
    }

    __shared__ float4 lsum[4][NQ];
    __shared__ float4 lsq[4][NQ];
    lsum[rl][q] = sum;
    lsq[rl][q]  = sq;
    __syncthreads();

    if (rl == 0) {
        float4 a0 = lsum[0][q], a1 = lsum[1][q], a2 = lsum[2][q], a3 = lsum[3][q];
        float4 q0 = lsq[0][q],  q1 = lsq[1][q],  q2 = lsq[2][q],  q3 = lsq[3][q];
        float4 ts, tq;
        ts.x = a0.x + a1.x + a2.x + a3.x;  ts.y = a0.y + a1.y + a2.y + a3.y;
        ts.z = a0.z + a1.z + a2.z + a3.z;  ts.w = a0.w + a1.w + a2.w + a3.w;
        tq.x = q0.x + q1.x + q2.x + q3.x;  tq.y = q0.y + q1.y + q2.y + q3.y;
        tq.z = q0.z + q1.z + q2.z + q3.z;  tq.w = q0.w + q1.w + q2.w + q3.w;
        reinterpret_cast<float4*>(psum)[(size_t)bid * NQ + q]   = ts;
        reinterpret_cast<float4*>(psumsq)[(size_t)bid * NQ + q] = tq;
    }
}

// ---------------------------------------------------------------------------
// Kernel 2: reduce each segment's contiguous chunk range -> scale/shift.
// ---------------------------------------------------------------------------
__global__ __launch_bounds__(BLK) void k_finalize(const float* __restrict__ psum,
                                                  const float* __restrict__ psumsq,
                                                  const int* __restrict__ off,
                                                  const int* __restrict__ bs,
                                                  const float* __restrict__ weight,
                                                  const float* __restrict__ bias,
                                                  float* __restrict__ scale,
                                                  float* __restrict__ shift) {
    const int seg = blockIdx.x;
    const int f   = threadIdx.x;
    const int b0 = bs[seg], b1 = bs[seg + 1];
    float s = 0.f, qq = 0.f;
    for (int b = b0; b < b1; ++b) {
        s  += psum[(size_t)b * NFEAT + f];
        qq += psumsq[(size_t)b * NFEAT + f];
    }
    const float cnt  = (float)(off[seg + 1] - off[seg]);
    const float m    = s / cnt;
    const float var  = fmaxf(qq / cnt - m * m, 0.f);
    const float rstd = rsqrtf(var + 1e-5f);
    const float sc   = rstd * weight[f];
    scale[(size_t)seg * NFEAT + f] = sc;
    shift[(size_t)seg * NFEAT + f] = bias[f] - m * sc;
}

// ---------------------------------------------------------------------------
// Kernel 3: normalize, chunks in REVERSE order. k_partial streamed x through
// L3 front-to-back, so the tail (~240 MB) is still resident; reading it first
// converts that portion of the re-read into L3 hits instead of HBM fetches.
// Non-temporal out stores keep the write stream from evicting that tail.
// ---------------------------------------------------------------------------
__global__ __launch_bounds__(BLK) void k_norm(const float* __restrict__ x,
                                              const int* __restrict__ off,
                                              const int* __restrict__ bs,
                                              const int* __restrict__ nblk,
                                              int B,
                                              const float* __restrict__ scale,
                                              const float* __restrict__ shift,
                                              float* __restrict__ out) {
    const int nch = *nblk;
    const int bid = blockIdx.x;
    if (bid >= nch) return;
    const int c = nch - 1 - bid;          // reverse: tail of x first (L3-hot)

    const int seg = find_seg(bs, B, c);
    const int r0 = off[seg] + (c - bs[seg]) * CH;
    const int r1 = min(r0 + CH, off[seg + 1]);

    const int rl = threadIdx.x >> 6;
    const int q  = threadIdx.x & 63;

    const float4 sc = reinterpret_cast<const float4*>(scale)[(size_t)seg * NQ + q];
    const float4 sh = reinterpret_cast<const float4*>(shift)[(size_t)seg * NQ + q];

    const float4* x4 = reinterpret_cast<const float4*>(x);
    float4* o4 = reinterpret_cast<float4*>(out);
    #pragma unroll 8
    for (int r = r0 + rl; r < r1; r += 4) {
        const size_t idx = (size_t)r * NQ + q;
        float4 v = x4[idx];
        float4 o;
        o.x = v.x * sc.x + sh.x;
        o.y = v.y * sc.y + sh.y;
        o.z = v.z * sc.z + sh.z;
        o.w = v.w * sc.w + sh.w;
        nt_store4(&o4[idx], o);
    }
}

extern "C" void kernel_launch(void* const* d_in, const int* in_sizes, int n_in,
                              void* d_out, int out_size, void* d_ws, size_t ws_size,
                              hipStream_t stream) {
    const float* x       = (const float*)d_in[0];
    const int*   lengths = (const int*)d_in[1];
    const float* weight  = (const float*)d_in[2];
    const float* bias    = (const float*)d_in[3];
    float*       out     = (float*)d_out;

    const int B = in_sizes[1];               // 128
    const int N = in_sizes[0] / NFEAT;       // 524288
    const int maxCh = N / CH + B;            // chunk upper bound

    // ws layout
    char* ws = (char*)d_ws;
    int*   off    = (int*)ws;                                  // B+1
    int*   bs     = off + 160;                                 // B+1
    int*   nblk   = bs + 160;                                  // 1
    float* scale  = (float*)(ws + 4096);                       // B*F
    float* shift  = scale + (size_t)B * NFEAT;                 // B*F
    float* psum   = shift + (size_t)B * NFEAT;                 // maxCh*F
    float* psumsq = psum + (size_t)maxCh * NFEAT;              // maxCh*F

    k_setup<<<1, BLK, 0, stream>>>(lengths, B, off, bs, nblk);
    k_partial<<<maxCh, BLK, 0, stream>>>(x, off, bs, nblk, B, psum, psumsq);
    k_finalize<<<B, BLK, 0, stream>>>(psum, psumsq, off, bs, weight, bias, scale, shift);
    k_norm<<<maxCh, BLK, 0, stream>>>(x, off, bs, nblk, B, scale, shift, out);
}